// Round 19
// baseline (602.517 us; speedup 1.0000x reference)
//
#include <hip/hip_runtime.h>
#include <hip/hip_bf16.h>
#include <math.h>

#define IGNORE_INDEX (-100)

constexpr int BT = 2048, H = 4096, V = 32000;
constexpr int BM = 256, BN = 256, BK = 64;
constexpr int KT = H / BK;            // 64 k-tiles
constexpr int MT2 = BT / BM;          // 8
constexpr int NT2 = V / BN;           // 125
constexpr int NCHUNK = NT2 * 4;       // 500 partial chunks/row (64 cols each)

typedef int   i32x4  __attribute__((ext_vector_type(4)));
typedef int   i32x8  __attribute__((ext_vector_type(8)));
typedef float f32x16 __attribute__((ext_vector_type(16)));

// e8m0 scale byte for 2^-7 (operands are pre-scaled by 2^7 at conversion)
#define SC8 120

__device__ __forceinline__ void gload_lds16(const char* g, char* l) {
  __builtin_amdgcn_global_load_lds(
      (const __attribute__((address_space(1))) unsigned int*)(g),
      (__attribute__((address_space(3))) unsigned int*)(l), 16, 0, 0);
}

#define BAR()        asm volatile("s_barrier" ::: "memory")
#define WAIT_VM(N)   asm volatile("s_waitcnt vmcnt(" #N ")" ::: "memory")
#define SB0()        __builtin_amdgcn_sched_barrier(0)

// ---------------------------------------------------------------------------
// fp32 -> fp8 e4m3 (OCP) bulk convert with x128 pre-scale  (r11-verified)
// ---------------------------------------------------------------------------
__global__ __launch_bounds__(256)
void convert_fp8(const float* __restrict__ src, char* __restrict__ dst,
                 int n8) {
  int i = blockIdx.x * blockDim.x + threadIdx.x;
  const int stride = gridDim.x * blockDim.x;
  for (; i < n8; i += stride) {
    const float4 f0 = ((const float4*)src)[2 * i];
    const float4 f1 = ((const float4*)src)[2 * i + 1];
    const float S = 128.f;
    int lo = 0, hi = 0;
    lo = __builtin_amdgcn_cvt_pk_fp8_f32(f0.x * S, f0.y * S, lo, false);
    lo = __builtin_amdgcn_cvt_pk_fp8_f32(f0.z * S, f0.w * S, lo, true);
    hi = __builtin_amdgcn_cvt_pk_fp8_f32(f1.x * S, f1.y * S, hi, false);
    hi = __builtin_amdgcn_cvt_pk_fp8_f32(f1.z * S, f1.w * S, hi, true);
    int2 v; v.x = lo; v.y = hi;
    ((int2*)dst)[i] = v;
  }
}

// ---------------------------------------------------------------------------
// 256x256 MX-fp8 GEMM — r11's verified data paths (LDS [buf:2][256][64],
// swizzle slot(row,q)=q^((row>>1)&3) BOTH sides) on r12's VERIFIED phase
// shape: ONE barrier per K-tile, reads PRE-barrier:
//   phase(i, buf b): STAGE(b^1 <- tile t+1)  [4 gloads, top]
//                    reads(b) + 8 MFMA       [stage latency hides here]
//                    SB0; VM(0); BAR         [stage drained; MFMA pinned]
// Audit: landing -- stages(i) drained at VM(0)@i, BAR(i) orders cross-wave
// before reads(i+1). Overwrite -- stage(b^1)@i+1 is post-BAR(i); reads(b^1)@i
// drained before their MFMAs (lgkm operand waits), MFMAs pinned pre-BAR(i)
// by SB0 (rule #18 fence). Registers/LDS identical to r11.
// ---------------------------------------------------------------------------
__global__ __launch_bounds__(512, 2)
void gemm_lse_m(const char* __restrict__ Wq,   // (V,H) fp8, pre-scaled x128
                const char* __restrict__ Xq,   // (BT,H) fp8, pre-scaled x128
                const int* __restrict__ target,
                const float* __restrict__ bias,
                float* __restrict__ pM, float* __restrict__ pS,
                float* __restrict__ gold)
{
  __shared__ char As[32768];   // [buf:2][256][64]
  __shared__ char Bs[32768];

  const int tid  = threadIdx.x;
  const int lane = tid & 63;
  const int wid  = tid >> 6;
  const int wr   = wid >> 2;        // 0..1 : rows [wr*128, +128)
  const int wcol = wid & 3;         // 0..3 : cols [wcol*64, +64)

  // XCD swizzle: nwg = 1000 = 8*125, bijective
  const int bid = (int)blockIdx.x;
  const int swz = (bid & 7) * 125 + (bid >> 3);
  const int mt = swz & (MT2 - 1);
  const int nt = swz >> 3;
  const int m0 = mt * BM, n0 = nt * BN;

  const int l31 = lane & 31;
  const int h   = lane >> 5;        // k-half owner: k in [h*32, h*32+32)
  const int r2  = (l31 >> 1) & 3;   // (row>>1)&3 (invariant under +8 rows)
  const int s0  = ((2 * h) ^ r2) << 4;       // stored slot of k-bytes 0..15
  const int s1  = ((2 * h + 1) ^ r2) << 4;   // stored slot of k-bytes 16..31
  const int abase = (wr * 128 + l31) * 64;
  const int bbase = (wcol * 64 + l31) * 64;

  // staging: lane covers row (lane>>2), slot lane&3; source pre-swizzled:
  // q = slot ^ ((row>>1)&3) = (lane&3) ^ ((lane>>3)&3)
  const int srow  = lane >> 2;
  const int sslot = ((lane & 3) ^ ((lane >> 3) & 3)) << 4;

  const char* asrc = Xq + (size_t)(m0 + wid * 32 + srow) * H + sslot;
  const char* bsrc = Wq + (size_t)(n0 + wid * 32 + srow) * H + sslot;

  f32x16 acc[4][2] = {};
  i32x8 aF0, aF1, bF0, bF1;

#define STAGE_A(BUF, DT)                                                      \
  { gload_lds16(asrc + (DT) * BK,                                             \
                &As[(BUF) * 16384 + wid * 2048 + lane * 16]);                 \
    gload_lds16(asrc + (size_t)16 * H + (DT) * BK,                            \
                &As[(BUF) * 16384 + wid * 2048 + 1024 + lane * 16]); }

#define STAGE_B(BUF, DT)                                                      \
  { gload_lds16(bsrc + (DT) * BK,                                             \
                &Bs[(BUF) * 16384 + wid * 2048 + lane * 16]);                 \
    gload_lds16(bsrc + (size_t)16 * H + (DT) * BK,                            \
                &Bs[(BUF) * 16384 + wid * 2048 + 1024 + lane * 16]); }

#define RDA(DST, BUF, MI)                                                     \
  { i32x4 lo = *(const i32x4*)&As[(BUF) * 16384 + abase + (MI) * 2048 + s0];  \
    i32x4 hi = *(const i32x4*)&As[(BUF) * 16384 + abase + (MI) * 2048 + s1];  \
    DST[0] = lo[0]; DST[1] = lo[1]; DST[2] = lo[2]; DST[3] = lo[3];           \
    DST[4] = hi[0]; DST[5] = hi[1]; DST[6] = hi[2]; DST[7] = hi[3]; }

#define RDB(DST, BUF, NJ)                                                     \
  { i32x4 lo = *(const i32x4*)&Bs[(BUF) * 16384 + bbase + (NJ) * 2048 + s0];  \
    i32x4 hi = *(const i32x4*)&Bs[(BUF) * 16384 + bbase + (NJ) * 2048 + s1];  \
    DST[0] = lo[0]; DST[1] = lo[1]; DST[2] = lo[2]; DST[3] = lo[3];           \
    DST[4] = hi[0]; DST[5] = hi[1]; DST[6] = hi[2]; DST[7] = hi[3]; }

#define MFMA4(MH)                                                             \
  { __builtin_amdgcn_s_setprio(1);                                            \
    acc[(MH)*2+0][0] = __builtin_amdgcn_mfma_scale_f32_32x32x64_f8f6f4(       \
        aF0, bF0, acc[(MH)*2+0][0], 0, 0, 0, SC8, 0, SC8);                    \
    acc[(MH)*2+0][1] = __builtin_amdgcn_mfma_scale_f32_32x32x64_f8f6f4(       \
        aF0, bF1, acc[(MH)*2+0][1], 0, 0, 0, SC8, 0, SC8);                    \
    acc[(MH)*2+1][0] = __builtin_amdgcn_mfma_scale_f32_32x32x64_f8f6f4(       \
        aF1, bF0, acc[(MH)*2+1][0], 0, 0, 0, SC8, 0, SC8);                    \
    acc[(MH)*2+1][1] = __builtin_amdgcn_mfma_scale_f32_32x32x64_f8f6f4(       \
        aF1, bF1, acc[(MH)*2+1][1], 0, 0, 0, SC8, 0, SC8);                    \
    __builtin_amdgcn_s_setprio(0); }

// full K-tile phase: compute buf B_, stage buf B_^1 <- rel-tile DT.
// Stage at top (latency hides under reads+MFMA); reads pinned pre-BAR via
// operand-lgkm + SB0; VM(0) drains this phase's 4 stage-loads before BAR.
#define PHASE(B_, DT)                                                         \
  { STAGE_B((B_) ^ 1, DT); STAGE_A((B_) ^ 1, DT);                             \
    RDA(aF0, B_, 0); RDA(aF1, B_, 1); RDB(bF0, B_, 0); RDB(bF1, B_, 1);       \
    MFMA4(0);                                                                 \
    RDA(aF0, B_, 2); RDA(aF1, B_, 3);                                         \
    MFMA4(1);                                                                 \
    SB0(); WAIT_VM(0); BAR(); }

  // ---- prologue: tile0 -> buf0, drain, barrier
  STAGE_B(0, 0); STAGE_A(0, 0);
  WAIT_VM(0);
  BAR();

  // ---- main loop: 2 K-tiles/iter, ONE barrier per K-tile
  for (int t = 0; t <= KT - 4; t += 2) {
    PHASE(0, 1);                    // compute tile t   (b0), stage t+1 -> b1
    PHASE(1, 2);                    // compute tile t+1 (b1), stage t+2 -> b0
    asrc += 2 * BK; bsrc += 2 * BK;
  }
  // ---- tail (asrc/bsrc at tile KT-2 base)
  PHASE(0, 1);                      // compute KT-2 (b0), stage KT-1 -> b1
  // tile KT-1 (b1): reads only — stage drained by PHASE's VM(0)+BAR
  RDA(aF0, 1, 0); RDA(aF1, 1, 1); RDB(bF0, 1, 0); RDB(bF1, 1, 1);
  MFMA4(0);
  RDA(aF0, 1, 2); RDA(aF1, 1, 3);
  MFMA4(1);

#undef PHASE
#undef STAGE_A
#undef STAGE_B
#undef RDA
#undef RDB
#undef MFMA4

  // ---- epilogue (32x32 C/D: col=lane&31, row=(r&3)+8*(r>>2)+4*h) — verified
  const int colbase = n0 + wcol * 64;
  float bv[2];
#pragma unroll
  for (int nj = 0; nj < 2; ++nj) bv[nj] = bias[colbase + nj * 32 + l31];

  const int chunk = nt * 4 + wcol;
#pragma unroll
  for (int mi = 0; mi < 4; ++mi) {
#pragma unroll
    for (int r = 0; r < 16; ++r) {
      const int row = m0 + wr * 128 + mi * 32 + (r & 3) + 8 * (r >> 2) + 4 * h;
      const float v0 = acc[mi][0][r] + bv[0];
      const float v1 = acc[mi][1][r] + bv[1];
      float mx = fmaxf(v0, v1);
#pragma unroll
      for (int d = 1; d < 32; d <<= 1) mx = fmaxf(mx, __shfl_xor(mx, d));
      float s = expf(v0 - mx) + expf(v1 - mx);
#pragma unroll
      for (int d = 1; d < 32; d <<= 1) s += __shfl_xor(s, d);
      if (l31 == 0) {
        pM[(size_t)row * NCHUNK + chunk] = mx;
        pS[(size_t)row * NCHUNK + chunk] = s;
      }
      const int t = target[row];
      const int d0 = t - colbase;
      if (d0 >= 0 && d0 < 64 && l31 == (d0 & 31)) {
        gold[row] = (d0 >> 5) ? v1 : v0;
      }
    }
  }
}

// one wave per row: combine 500 (max, sumexp) chunks -> rowterm
__global__ __launch_bounds__(256)
void reduce_lse(const float* __restrict__ pM, const float* __restrict__ pS,
                const float* __restrict__ gold, const int* __restrict__ target,
                const float* __restrict__ lw, float* __restrict__ rowterm)
{
  const int wid = threadIdx.x >> 6, lane = threadIdx.x & 63;
  const int row = blockIdx.x * 4 + wid;
  if (row >= BT) return;
  const float* pm = pM + (size_t)row * NCHUNK;
  const float* ps = pS + (size_t)row * NCHUNK;
  float m = -INFINITY;
  for (int c2 = lane; c2 < NCHUNK; c2 += 64) m = fmaxf(m, pm[c2]);
#pragma unroll
  for (int d = 1; d < 64; d <<= 1) m = fmaxf(m, __shfl_xor(m, d));
  float s = 0.f;
  for (int c2 = lane; c2 < NCHUNK; c2 += 64) s += ps[c2] * expf(pm[c2] - m);
#pragma unroll
  for (int d = 1; d < 64; d <<= 1) s += __shfl_xor(s, d);
  if (lane == 0) {
    const int t = target[row];
    float term = 0.f;
    if (t != IGNORE_INDEX) term = (m + logf(s) - gold[row]) * lw[row];
    rowterm[row] = term;
  }
}

// single-block deterministic finalize
__global__ __launch_bounds__(256)
void finalize(const float* __restrict__ rowterm, const int* __restrict__ target,
              const float* __restrict__ rsw, const int* __restrict__ gas,
              float* __restrict__ out)
{
  __shared__ float sred[4];
  __shared__ int cred[4];
  const int tid = threadIdx.x;
  float s = 0.f;
  int cnt = 0;
  for (int i = tid; i < BT; i += 256) {
    s += rowterm[i];
    cnt += (target[i] != IGNORE_INDEX) ? 1 : 0;
  }
#pragma unroll
  for (int d = 1; d < 64; d <<= 1) {
    s += __shfl_xor(s, d);
    cnt += __shfl_xor(cnt, d);
  }
  const int wid = tid >> 6, lane = tid & 63;
  if (lane == 0) { sred[wid] = s; cred[wid] = cnt; }
  __syncthreads();
  if (tid == 0) {
    const float st = sred[0] + sred[1] + sred[2] + sred[3];
    const int ct = cred[0] + cred[1] + cred[2] + cred[3];
    const float n = (float)((ct > 0) ? ct : 1);
    const float rs = rsw[0];
    float loss = (rs == 0.f) ? 0.f : (st / n) / rs;
    loss /= (float)gas[0];
    out[0] = loss;
  }
}

extern "C" void kernel_launch(void* const* d_in, const int* in_sizes, int n_in,
                              void* d_out, int out_size, void* d_ws, size_t ws_size,
                              hipStream_t stream)
{
  const float* Wt     = (const float*)d_in[0];  // lin_weight (V,H)
  const float* X      = (const float*)d_in[1];  // _input (BT,H)
  const int*   target = (const int*)d_in[2];
  const float* bias   = (const float*)d_in[3];
  const float* lw     = (const float*)d_in[4];
  const float* rsw    = (const float*)d_in[5];
  const int*   gas    = (const int*)d_in[6];
  float* out = (float*)d_out;

  const size_t nW = (size_t)V * H, nX = (size_t)BT * H;

  char* Wq = (char*)d_ws;                       // V*H fp8
  char* Xq = Wq + nW;                           // BT*H fp8
  float* pM = (float*)(Xq + nX);
  float* pS = pM + (size_t)BT * NCHUNK;
  float* gold = pS + (size_t)BT * NCHUNK;
  float* rowterm = gold + BT;

  convert_fp8<<<dim3(2048), dim3(256), 0, stream>>>(Wt, Wq, (int)(nW / 8));
  convert_fp8<<<dim3(256), dim3(256), 0, stream>>>(X, Xq, (int)(nX / 8));
  gemm_lse_m<<<dim3(MT2 * NT2), dim3(512), 0, stream>>>(Wq, Xq, target,
                                                        bias, pM, pS, gold);
  reduce_lse<<<dim3(BT / 4), dim3(256), 0, stream>>>(pM, pS, gold, target, lw,
                                                     rowterm);
  finalize<<<dim3(1), dim3(256), 0, stream>>>(rowterm, target, rsw, gas, out);
}